// Round 2
// baseline (563.038 us; speedup 1.0000x reference)
//
#include <hip/hip_runtime.h>

#define BLK     256
#define TBATCH  4       // batch rows per block (1 per wave)
#define LLEN    50      // act-list length
#define DIM     256     // embedding dim
#define DIM4    64      // DIM / 4 (float4 units)

__device__ __forceinline__ float sigmoidf_(float x) {
    return 1.0f / (1.0f + __expf(-x));
}

__global__ __launch_bounds__(BLK) void slotgate_fused(
    const int* __restrict__ acts_request,   // (B, 50)
    const int* __restrict__ acts_slot,      // (B, 50)
    const int* __restrict__ acts_value,     // (B, 50)
    const int* __restrict__ slot_names,     // (B, 4)
    const float* __restrict__ emb,          // (V, 256)
    const float* __restrict__ w1,           // (256, 256) row-major [i][j]
    const float* __restrict__ w2,           // (256, 256)
    float* __restrict__ out)                // (B, 4, 256)
{
    __shared__ int    lds_iq[TBATCH * LLEN];
    __shared__ int    lds_is[TBATCH * LLEN];
    __shared__ int    lds_iv[TBATCH * LLEN];
    __shared__ float4 lds_tq [TBATCH * DIM4];   // t_q tile
    __shared__ float4 lds_tsv[TBATCH * DIM4];   // t_s + t_v tile

    const int tid  = threadIdx.x;
    const int b0   = blockIdx.x * TBATCH;
    const int wv   = tid >> 6;    // wave id 0..3 == batch row within block
    const int lane = tid & 63;

    // ---- stage indices (coalesced) ----
    for (int t = tid; t < TBATCH * LLEN; t += BLK) {
        lds_iq[t] = acts_request[b0 * LLEN + t];
        lds_is[t] = acts_slot   [b0 * LLEN + t];
        lds_iv[t] = acts_value  [b0 * LLEN + t];
    }
    __syncthreads();

    const float4* emb4 = (const float4*)emb;

    // ---- gather phase: wave wv owns batch row (b0 + wv) ----
    // lane = float4 column -> each row read is one coalesced 1KB wave load.
    // unroll x5 keeps ~15 independent row-loads in flight per wave.
    float4 aq  = make_float4(0.f, 0.f, 0.f, 0.f);
    float4 asv = make_float4(0.f, 0.f, 0.f, 0.f);
    const int* iqp = &lds_iq[wv * LLEN];
    const int* isp = &lds_is[wv * LLEN];
    const int* ivp = &lds_iv[wv * LLEN];
    #pragma unroll 5
    for (int l = 0; l < LLEN; l++) {
        const int iq = iqp[l];
        const int is = isp[l];
        const int iv = ivp[l];
        float4 vq = emb4[iq * DIM4 + lane];
        float4 vs = emb4[is * DIM4 + lane];
        float4 vv = emb4[iv * DIM4 + lane];
        aq.x  += vq.x;        aq.y  += vq.y;        aq.z  += vq.z;        aq.w  += vq.w;
        asv.x += vs.x + vv.x; asv.y += vs.y + vv.y; asv.z += vs.z + vv.z; asv.w += vs.w + vv.w;
    }
    lds_tq [wv * DIM4 + lane] = aq;
    lds_tsv[wv * DIM4 + lane] = asv;
    __syncthreads();

    // ---- matmul phase: thread computes 4 i-rows for batch row tb ----
    const int ti  = tid & 63;   // i-group: i = 4*ti .. 4*ti+3
    const int tb  = tid >> 6;   // batch row within block (wave-uniform)
    const int i0  = ti * 4;

    float accq [4] = {};   // g_q [i0..i0+3]
    float accsv[4] = {};   // g_sv

    const float4* w1f = (const float4*)w1;
    const float4* w2f = (const float4*)w2;

    for (int j4 = 0; j4 < DIM4; j4++) {
        float4 tq = lds_tq [tb * DIM4 + j4];   // wave-uniform broadcast b128
        float4 ts = lds_tsv[tb * DIM4 + j4];
        #pragma unroll
        for (int r = 0; r < 4; r++) {
            float4 wa = w1f[(i0 + r) * DIM4 + j4];
            float4 wb = w2f[(i0 + r) * DIM4 + j4];
            accq [r] += wa.x * tq.x + wa.y * tq.y + wa.z * tq.z + wa.w * tq.w;
            accsv[r] += wb.x * ts.x + wb.y * ts.y + wb.z * ts.z + wb.w * ts.w;
        }
    }

    // ---- epilogue: gates = c_s + sig(c_s*g_q) + sig(c_s*g_sv) ----
    float4* out4 = (float4*)out;
    const int b = b0 + tb;
    #pragma unroll
    for (int s = 0; s < 4; s++) {
        const int slot = slot_names[b * 4 + s];
        float4 cs = emb4[slot * DIM4 + ti];
        float4 g;
        g.x = cs.x + sigmoidf_(cs.x * accq[0]) + sigmoidf_(cs.x * accsv[0]);
        g.y = cs.y + sigmoidf_(cs.y * accq[1]) + sigmoidf_(cs.y * accsv[1]);
        g.z = cs.z + sigmoidf_(cs.z * accq[2]) + sigmoidf_(cs.z * accsv[2]);
        g.w = cs.w + sigmoidf_(cs.w * accq[3]) + sigmoidf_(cs.w * accsv[3]);
        out4[(b * 4 + s) * DIM4 + ti] = g;
    }
}

extern "C" void kernel_launch(void* const* d_in, const int* in_sizes, int n_in,
                              void* d_out, int out_size, void* d_ws, size_t ws_size,
                              hipStream_t stream) {
    const int*   acts_request = (const int*)  d_in[0];
    const int*   acts_slot    = (const int*)  d_in[1];
    const int*   acts_value   = (const int*)  d_in[2];
    const int*   slot_names   = (const int*)  d_in[3];
    const float* ontology_emb = (const float*)d_in[4];
    const float* w1           = (const float*)d_in[5];
    const float* w2           = (const float*)d_in[6];
    float*       out          = (float*)      d_out;

    const int bsz  = in_sizes[0] / LLEN;     // 4096
    const int nblk = bsz / TBATCH;           // 1024

    slotgate_fused<<<nblk, BLK, 0, stream>>>(
        acts_request, acts_slot, acts_value, slot_names,
        ontology_emb, w1, w2, out);
}

// Round 3
// 252.525 us; speedup vs baseline: 2.2296x; 2.2296x over previous
//
#include <hip/hip_runtime.h>

#define BLK     256
#define TBATCH  4       // batch rows per block (1 per wave in gather)
#define LLEN    50      // act-list length
#define DIM     256     // embedding dim
#define DIM4    64      // DIM / 4 (float4 units)

__device__ __forceinline__ float sigmoidf_(float x) {
    return 1.0f / (1.0f + __expf(-x));
}

// ---- tiny transpose: w (256x256 row-major [i][j]) -> wT ([j][i]) in d_ws ----
__global__ __launch_bounds__(256) void transpose_w(
    const float* __restrict__ w1, const float* __restrict__ w2,
    float* __restrict__ wt1, float* __restrict__ wt2)
{
    __shared__ float tile[64][65];          // +1 pad: conflict-free transpose read
    const int m  = blockIdx.x >> 4;         // matrix select
    const int t  = blockIdx.x & 15;
    const int ti = (t >> 2) * 64;           // i-tile origin
    const int tj = (t & 3) * 64;            // j-tile origin
    const float* src = m ? w2  : w1;
    float*       dst = m ? wt2 : wt1;
    const int tx = threadIdx.x & 63;
    const int ty = threadIdx.x >> 6;        // 0..3
    #pragma unroll
    for (int r = 0; r < 64; r += 4) {
        const int row = r + ty;
        tile[row][tx] = src[(ti + row) * DIM + tj + tx];   // coalesced read
    }
    __syncthreads();
    #pragma unroll
    for (int r = 0; r < 64; r += 4) {
        const int row = r + ty;
        dst[(tj + row) * DIM + ti + tx] = tile[tx][row];   // coalesced write
    }
}

__global__ __launch_bounds__(BLK, 4) void slotgate_fused(
    const int* __restrict__ acts_request,   // (B, 50)
    const int* __restrict__ acts_slot,      // (B, 50)
    const int* __restrict__ acts_value,     // (B, 50)
    const int* __restrict__ slot_names,     // (B, 4)
    const float* __restrict__ emb,          // (V, 256)
    const float* __restrict__ wt1,          // (256, 256) TRANSPOSED [j][i]
    const float* __restrict__ wt2,          // (256, 256) TRANSPOSED [j][i]
    float* __restrict__ out)                // (B, 4, 256)
{
    __shared__ int    lds_iq[TBATCH * LLEN];
    __shared__ int    lds_is[TBATCH * LLEN];
    __shared__ int    lds_iv[TBATCH * LLEN];
    __shared__ float4 lds_tq [TBATCH * DIM4];   // t_q tile       [row][j4]
    __shared__ float4 lds_tsv[TBATCH * DIM4];   // t_s + t_v tile [row][j4]
    __shared__ float  lds_gq [TBATCH * DIM];    // g_q  [row][i]
    __shared__ float  lds_gsv[TBATCH * DIM];    // g_sv [row][i]

    const int tid  = threadIdx.x;
    const int b0   = blockIdx.x * TBATCH;
    const int wv   = tid >> 6;    // wave id 0..3
    const int lane = tid & 63;

    // ---- stage indices (coalesced) ----
    for (int t = tid; t < TBATCH * LLEN; t += BLK) {
        lds_iq[t] = acts_request[b0 * LLEN + t];
        lds_is[t] = acts_slot   [b0 * LLEN + t];
        lds_iv[t] = acts_value  [b0 * LLEN + t];
    }
    __syncthreads();

    const float4* emb4 = (const float4*)emb;

    // ---- gather: wave wv owns batch row (b0+wv); lane = float4 column ----
    {
        float4 aq  = make_float4(0.f, 0.f, 0.f, 0.f);
        float4 asv = make_float4(0.f, 0.f, 0.f, 0.f);
        const int* iqp = &lds_iq[wv * LLEN];
        const int* isp = &lds_is[wv * LLEN];
        const int* ivp = &lds_iv[wv * LLEN];
        #pragma unroll 5
        for (int l = 0; l < LLEN; l++) {
            float4 vq = emb4[iqp[l] * DIM4 + lane];
            float4 vs = emb4[isp[l] * DIM4 + lane];
            float4 vv = emb4[ivp[l] * DIM4 + lane];
            aq.x  += vq.x;        aq.y  += vq.y;        aq.z  += vq.z;        aq.w  += vq.w;
            asv.x += vs.x + vv.x; asv.y += vs.y + vv.y; asv.z += vs.z + vv.z; asv.w += vs.w + vv.w;
        }
        lds_tq [wv * DIM4 + lane] = aq;
        lds_tsv[wv * DIM4 + lane] = asv;
    }
    __syncthreads();

    // ---- matmul: wave wv owns i-slice [64*wv, 64*wv+64); lane owns one i ----
    // wT reads are lane-coalesced (256B/wave); t reads are wave-uniform LDS
    // broadcasts; all 4 batch rows amortize each w load.
    {
        const int i = wv * 64 + lane;
        float accq [TBATCH] = {};
        float accsv[TBATCH] = {};
        for (int j4 = 0; j4 < DIM4; j4++) {
            float tqa[TBATCH][4], tsa[TBATCH][4];
            #pragma unroll
            for (int r = 0; r < TBATCH; r++) {
                float4 v = lds_tq [r * DIM4 + j4];   // uniform -> broadcast
                tqa[r][0] = v.x; tqa[r][1] = v.y; tqa[r][2] = v.z; tqa[r][3] = v.w;
                float4 u = lds_tsv[r * DIM4 + j4];
                tsa[r][0] = u.x; tsa[r][1] = u.y; tsa[r][2] = u.z; tsa[r][3] = u.w;
            }
            #pragma unroll
            for (int k = 0; k < 4; k++) {
                const int j = j4 * 4 + k;
                const float w1v = wt1[j * DIM + i];  // coalesced across lanes
                const float w2v = wt2[j * DIM + i];
                #pragma unroll
                for (int r = 0; r < TBATCH; r++) {
                    accq [r] += w1v * tqa[r][k];
                    accsv[r] += w2v * tsa[r][k];
                }
            }
        }
        #pragma unroll
        for (int r = 0; r < TBATCH; r++) {
            lds_gq [r * DIM + i] = accq [r];         // contiguous -> no conflict
            lds_gsv[r * DIM + i] = accsv[r];
        }
    }
    __syncthreads();

    // ---- epilogue: gates = c_s + sig(c_s*g_q) + sig(c_s*g_sv) ----
    {
        const int tb   = tid >> 6;      // batch row within block
        const int tcol = tid & 63;      // float4 column
        const int b    = b0 + tb;
        const float4* gq4 = (const float4*)lds_gq;
        const float4* gs4 = (const float4*)lds_gsv;
        const float4 gq = gq4[tb * DIM4 + tcol];
        const float4 gs = gs4[tb * DIM4 + tcol];
        float4* out4 = (float4*)out;
        #pragma unroll
        for (int s = 0; s < 4; s++) {
            const int slot = slot_names[b * 4 + s];
            float4 cs = emb4[slot * DIM4 + tcol];
            float4 g;
            g.x = cs.x + sigmoidf_(cs.x * gq.x) + sigmoidf_(cs.x * gs.x);
            g.y = cs.y + sigmoidf_(cs.y * gq.y) + sigmoidf_(cs.y * gs.y);
            g.z = cs.z + sigmoidf_(cs.z * gq.z) + sigmoidf_(cs.z * gs.z);
            g.w = cs.w + sigmoidf_(cs.w * gq.w) + sigmoidf_(cs.w * gs.w);
            out4[(b * 4 + s) * DIM4 + tcol] = g;
        }
    }
}

extern "C" void kernel_launch(void* const* d_in, const int* in_sizes, int n_in,
                              void* d_out, int out_size, void* d_ws, size_t ws_size,
                              hipStream_t stream) {
    const int*   acts_request = (const int*)  d_in[0];
    const int*   acts_slot    = (const int*)  d_in[1];
    const int*   acts_value   = (const int*)  d_in[2];
    const int*   slot_names   = (const int*)  d_in[3];
    const float* ontology_emb = (const float*)d_in[4];
    const float* w1           = (const float*)d_in[5];
    const float* w2           = (const float*)d_in[6];
    float*       out          = (float*)      d_out;

    float* wt1 = (float*)d_ws;              // 256*256 floats = 256 KB
    float* wt2 = wt1 + DIM * DIM;           // another 256 KB

    const int bsz  = in_sizes[0] / LLEN;     // 4096
    const int nblk = bsz / TBATCH;           // 1024

    transpose_w<<<32, 256, 0, stream>>>(w1, w2, wt1, wt2);
    slotgate_fused<<<nblk, BLK, 0, stream>>>(
        acts_request, acts_slot, acts_value, slot_names,
        ontology_emb, wt1, wt2, out);
}